// Round 3
// baseline (1984.807 us; speedup 1.0000x reference)
//
#include <hip/hip_runtime.h>

typedef _Float16 f16;
typedef _Float16 f16x8 __attribute__((ext_vector_type(8)));
typedef _Float16 f16x2 __attribute__((ext_vector_type(2)));
typedef float    f32x4 __attribute__((ext_vector_type(4)));

// ws layout (bytes) -- R2 fix: b0p is 4096 f32 = 16384 B (was under-allocated
// 8192 B, so b0p[2048..4095] raced over gp[0..2047] = the j=0 tangent seed).
#define OFF_WHP   0u          // f16 [5][16nt][8kk][64lane][8e]   = 655360 B
#define OFF_WLP   655360u     // f16 [8kk][64lane][8e]            = 8192 B
#define OFF_W0P   663552u     // f32 [8kk][64lane][8e][4i]        = 65536 B
#define OFF_B0P   729088u     // f32 [8kk][64lane][8e]            = 16384 B
#define OFF_GP    745472u     // f32 [3j][8kk][64lane][8e]        = 49152 B
#define OFF_BHP   794624u     // f32 [5l][16nt][64lane][4r]       = 81920 B
                              // end = 876544 B total ws use

// k-slot map: slot (kk, lane-group g, elem e) -> k. Applied identically to
// A (weights, prepacked) and B (activations, built in-lane), so any bijection
// is mathematically valid. This particular one makes the MFMA D-output
// (n = nt*16 + g*4 + r) land exactly in next layer's B-slot (kk'=nt>>1,
// e'=(nt&1)*4+r) -- lane-local layer transition, no LDS/cross-lane.
__device__ __forceinline__ int phi(int kk, int g, int e){
  return (kk*2 + (e>>2))*16 + g*4 + (e&3);
}

__device__ __forceinline__ float tanh_fast(float z){
  // tanh(z) = 1 - 2/(exp2(2z*log2e)+1); exp2/rcp ~1ulp each, saturates right.
  float e = __builtin_amdgcn_exp2f(z * 2.885390081777927f);
  return 1.f - 2.f*__builtin_amdgcn_rcpf(e + 1.f);
}

__global__ void prepack(const float* __restrict__ W0, const float* __restrict__ b0,
                        const float* __restrict__ Wh, const float* __restrict__ bh,
                        const float* __restrict__ Wl, unsigned char* __restrict__ ws){
  int tid = blockIdx.x*256 + threadIdx.x;
  f16*   whp = (f16*)(ws + OFF_WHP);
  f16*   wlp = (f16*)(ws + OFF_WLP);
  float* w0p = (float*)(ws + OFF_W0P);
  float* b0p = (float*)(ws + OFF_B0P);
  float* gp  = (float*)(ws + OFF_GP);
  float* bhp = (float*)(ws + OFF_BHP);
  if (tid < 327680){                      // Wh fragments, f16
    int e=tid&7, lane=(tid>>3)&63, kk=(tid>>9)&7, nt=(tid>>12)&15, l=tid>>16;
    int k = phi(kk, lane>>4, e);
    int n = nt*16 + (lane&15);
    whp[tid] = (f16)Wh[(l*256 + k)*256 + n];
  } else if (tid < 331776){               // Wl fragments (N padded 3->16), f16
    int t = tid - 327680;
    int e=t&7, lane=(t>>3)&63, kk=t>>9;
    int k = phi(kk, lane>>4, e);
    int n = lane&15;
    wlp[t] = (n<3) ? (f16)Wl[k*3+n] : (f16)0.f;
  } else if (tid < 335872){               // W0 columns + b0 in slot order, f32
    int t = tid - 331776;
    int e=t&7, lane=(t>>3)&63, kk=t>>9;
    int k = phi(kk, lane>>4, e);
    #pragma unroll
    for(int i=0;i<4;i++) w0p[t*4+i] = W0[i*256+k];
    b0p[t] = b0[k];
  } else if (tid < 348160){               // g_j = W0[j,:] @ Wh[0], slot order, f32
    int t = tid - 335872;
    int e=t&7, lane=(t>>3)&63, kk=(t>>9)&7, j=t>>12;
    int k = phi(kk, lane>>4, e);
    float acc = 0.f;
    for(int k0=0;k0<256;k0++) acc = fmaf(W0[j*256+k0], Wh[k0*256+k], acc);
    gp[t] = acc;
  } else if (tid < 368640){               // bh in D-layout order, f32
    int t = tid - 348160;
    int r=t&3, lane=(t>>2)&63, nt=(t>>8)&15, l=t>>12;
    bhp[t] = bh[l*256 + nt*16 + (lane>>4)*4 + r];
  }
}

__global__ __launch_bounds__(256, 2) void velcurl(
    const float* __restrict__ x, const unsigned char* __restrict__ ws,
    float* __restrict__ out){
  const int lane  = threadIdx.x & 63;
  const int wid   = (blockIdx.x<<2) + (threadIdx.x>>6);  // global wave id
  const int sbase = wid<<4;                               // 16 samples/wave
  const int c0    = lane & 15;                            // this lane's sample col

  const f16x8* __restrict__ whp = (const f16x8*)(ws + OFF_WHP);
  const f16x8* __restrict__ wlp = (const f16x8*)(ws + OFF_WLP);
  const f32x4* __restrict__ w0p = (const f32x4*)(ws + OFF_W0P);
  const float* __restrict__ b0p = (const float*)(ws + OFF_B0P);
  const float* __restrict__ gp  = (const float*)(ws + OFF_GP);
  const f32x4* __restrict__ bhp = (const f32x4*)(ws + OFF_BHP);

  const f32x4 xv = ((const f32x4*)x)[sbase + c0];

  f16x8 st[4][8];        // state frags: [comp: h,t0,t1,t2][kk]
  f16x2 msk[16][2];      // 1-h^2 per nt, 4 r-values packed f16x2

  // ---- layer 0: h0 = x@W0 + b0, built directly in B-slot order ----
  #pragma unroll
  for(int kk=0;kk<8;kk++){
    f16x8 v;
    #pragma unroll
    for(int e=0;e<8;e++){
      f32x4 w = w0p[(kk*64+lane)*8+e];
      float b = b0p[(kk*64+lane)*8+e];
      float h = fmaf(xv[3],w[3], fmaf(xv[2],w[2], fmaf(xv[1],w[1], fmaf(xv[0],w[0], b))));
      v[e] = (f16)h;
    }
    st[0][kk] = v;
  }

  // ---- layer Wh0: primal MFMA sweep, then tangent init from g_j ----
  {
    f16x8 nst[8];
    #pragma unroll
    for(int nt=0;nt<16;nt++){
      f32x4 acc = {0.f,0.f,0.f,0.f};
      #pragma unroll
      for(int kk=0;kk<8;kk++)
        acc = __builtin_amdgcn_mfma_f32_16x16x32_f16(whp[(nt*8+kk)*64+lane], st[0][kk], acc, 0,0,0);
      f32x4 bv = bhp[nt*64+lane];
      #pragma unroll
      for(int r=0;r<4;r++){
        float h = tanh_fast(acc[r]+bv[r]);
        float m = 1.f - h*h;
        nst[nt>>1][(nt&1)*4+r] = (f16)h;
        msk[nt][r>>1][r&1] = (f16)m;
      }
    }
    #pragma unroll
    for(int kk=0;kk<8;kk++) st[0][kk]=nst[kk];
    #pragma unroll
    for(int c=1;c<4;c++){
      #pragma unroll
      for(int kk=0;kk<8;kk++){
        f16x8 v;
        #pragma unroll
        for(int e=0;e<8;e++){
          const int mt = kk*2 + (e>>2), r = e&3;
          float mv = (float)msk[mt][r>>1][r&1];
          float gv = gp[(((c-1)*8+kk)*64+lane)*8+e];
          v[e] = (f16)(mv*gv);
        }
        st[c][kk]=v;
      }
    }
  }

  // ---- layers Wh1..Wh4: 4 comps in lockstep ----
  #pragma unroll 1
  for(int l=1;l<5;l++){
    const f16x8* wl = whp + l*(16*8*64);
    const f32x4* bp = bhp + l*(16*64);
    #pragma unroll
    for(int c=0;c<4;c++){
      f16x8 nst[8];
      #pragma unroll
      for(int nt=0;nt<16;nt++){
        f32x4 acc = {0.f,0.f,0.f,0.f};
        #pragma unroll
        for(int kk=0;kk<8;kk++)
          acc = __builtin_amdgcn_mfma_f32_16x16x32_f16(wl[(nt*8+kk)*64+lane], st[c][kk], acc, 0,0,0);
        if(c==0){
          f32x4 bv = bp[nt*64+lane];
          #pragma unroll
          for(int r=0;r<4;r++){
            float h = tanh_fast(acc[r]+bv[r]);
            float m = 1.f - h*h;
            nst[nt>>1][(nt&1)*4+r] = (f16)h;
            msk[nt][r>>1][r&1] = (f16)m;
          }
        } else {
          #pragma unroll
          for(int r=0;r<4;r++){
            float mv = (float)msk[nt][r>>1][r&1];
            nst[nt>>1][(nt&1)*4+r] = (f16)(acc[r]*mv);
          }
        }
      }
      #pragma unroll
      for(int kk=0;kk<8;kk++) st[c][kk]=nst[kk];
    }
  }

  // ---- final layer: tangents only (a itself not needed), N padded to 16 ----
  f32x4 accT[3];
  #pragma unroll
  for(int c=1;c<4;c++){
    f32x4 acc = {0.f,0.f,0.f,0.f};
    #pragma unroll
    for(int kk=0;kk<8;kk++)
      acc = __builtin_amdgcn_mfma_f32_16x16x32_f16(wlp[kk*64+lane], st[c][kk], acc, 0,0,0);
    accT[c-1]=acc;
  }
  // D: col=lane&15=s, row=(lane>>4)*4+reg=n -> lanes 0..15 hold n=0..2 in regs
  if(lane<16){
    const int s = sbase + lane;
    out[s*3+0] = accT[1][2] - accT[2][1];  // da2/dx1 - da1/dx2
    out[s*3+1] = accT[2][0] - accT[0][2];  // da0/dx2 - da2/dx0
    out[s*3+2] = accT[0][1] - accT[1][0];  // da1/dx0 - da0/dx1
  }
}

extern "C" void kernel_launch(void* const* d_in, const int* in_sizes, int n_in,
                              void* d_out, int out_size, void* d_ws, size_t ws_size,
                              hipStream_t stream){
  const float* x  = (const float*)d_in[0];
  const float* W0 = (const float*)d_in[1];
  const float* b0 = (const float*)d_in[2];
  const float* Wh = (const float*)d_in[3];
  const float* bh = (const float*)d_in[4];
  const float* Wl = (const float*)d_in[5];
  // d_in[6] = bl: constant offset of a, curl kills it.
  prepack<<<1440, 256, 0, stream>>>(W0, b0, Wh, bh, Wl, (unsigned char*)d_ws);
  velcurl<<<65536/16/4, 256, 0, stream>>>(x, (const unsigned char*)d_ws, (float*)d_out);
}

// Round 4
// 387.046 us; speedup vs baseline: 5.1281x; 5.1281x over previous
//
#include <hip/hip_runtime.h>

typedef _Float16 f16;
typedef _Float16 f16x4 __attribute__((ext_vector_type(4)));
typedef _Float16 f16x8 __attribute__((ext_vector_type(8)));
typedef float    f32x4 __attribute__((ext_vector_type(4)));

// ws layout (bytes)
#define OFF_WHP   0u          // f16 [5][16nt][8kk][64lane][8e]   = 655360 B
#define OFF_WLP   655360u     // f16 [8kk][64lane][8e]            = 8192 B
#define OFF_W0P   663552u     // f32 [8kk][64lane][8e][4i]        = 65536 B
#define OFF_B0P   729088u     // f32 [8kk][64lane][8e]            = 16384 B
#define OFF_GP    745472u     // f32 [3j][8kk][64lane][8e]        = 49152 B
#define OFF_BHP   794624u     // f32 [5l][16nt][64lane][4r]       = 81920 B

// k-slot map: slot (kk, lane-group g, elem e) -> k = (2kk+(e>>2))*16+4g+(e&3).
// Applied identically to A (weights, prepacked) and B (activations), so the
// MFMA D-output (n = nt*16+4g+r) lands exactly in next layer's B-slot
// (kk'=nt>>1, e'=(nt&1)*4+r): lane-local layer transitions.
__device__ __forceinline__ int phi(int kk, int g, int e){
  return (kk*2 + (e>>2))*16 + g*4 + (e&3);
}

__device__ __forceinline__ float tanh_fast(float z){
  float e = __builtin_amdgcn_exp2f(z * 2.885390081777927f);
  return 1.f - 2.f*__builtin_amdgcn_rcpf(e + 1.f);
}

__global__ void prepack(const float* __restrict__ W0, const float* __restrict__ b0,
                        const float* __restrict__ Wh, const float* __restrict__ bh,
                        const float* __restrict__ Wl, unsigned char* __restrict__ ws){
  int tid = blockIdx.x*256 + threadIdx.x;
  f16*   whp = (f16*)(ws + OFF_WHP);
  f16*   wlp = (f16*)(ws + OFF_WLP);
  float* w0p = (float*)(ws + OFF_W0P);
  float* b0p = (float*)(ws + OFF_B0P);
  float* gp  = (float*)(ws + OFF_GP);
  float* bhp = (float*)(ws + OFF_BHP);
  if (tid < 327680){                      // Wh fragments, f16
    int e=tid&7, lane=(tid>>3)&63, kk=(tid>>9)&7, nt=(tid>>12)&15, l=tid>>16;
    int k = phi(kk, lane>>4, e);
    int n = nt*16 + (lane&15);
    whp[tid] = (f16)Wh[(l*256 + k)*256 + n];
  } else if (tid < 331776){               // Wl fragments (N padded 3->16), f16
    int t = tid - 327680;
    int e=t&7, lane=(t>>3)&63, kk=t>>9;
    int k = phi(kk, lane>>4, e);
    int n = lane&15;
    wlp[t] = (n<3) ? (f16)Wl[k*3+n] : (f16)0.f;
  } else if (tid < 335872){               // W0 columns + b0 in slot order, f32
    int t = tid - 331776;
    int e=t&7, lane=(t>>3)&63, kk=t>>9;
    int k = phi(kk, lane>>4, e);
    #pragma unroll
    for(int i=0;i<4;i++) w0p[t*4+i] = W0[i*256+k];
    b0p[t] = b0[k];
  } else if (tid < 348160){               // g_j = W0[j,:] @ Wh[0], slot order, f32
    int t = tid - 335872;
    int e=t&7, lane=(t>>3)&63, kk=(t>>9)&7, j=t>>12;
    int k = phi(kk, lane>>4, e);
    float acc = 0.f;
    for(int k0=0;k0<256;k0++) acc = fmaf(W0[j*256+k0], Wh[k0*256+k], acc);
    gp[t] = acc;
  } else if (tid < 368640){               // bh in D-layout order, f32
    int t = tid - 348160;
    int r=t&3, lane=(t>>2)&63, nt=(t>>8)&15, l=t>>12;
    bhp[t] = bh[l*256 + nt*16 + (lane>>4)*4 + r];
  }
}

// mask LDS byte offset: [s][n] f16, XOR-swizzled so the 8B mask ops spread banks
__device__ __forceinline__ int moff(int s, int n){
  return ((s<<9) + (n<<1)) ^ ((s&7)<<4);
}

// R4: comp-per-wave decomposition. Wave 0 = primal chain (publishes tanh'
// masks to LDS per layer), waves 1..3 = one tangent chain each. Per-wave
// register state is 2 frag-sets (64 VGPR) instead of 4 chains (128+) -> no
// scratch spill (R3 was 100% spill-bound: 7.5 GB scratch traffic @3.6TB/s).
__global__ __launch_bounds__(256, 2) void velcurl(
    const float* __restrict__ x, const unsigned char* __restrict__ ws,
    float* __restrict__ out){
  __shared__ __align__(16) char mbuf[2][8192];   // masks, double-buffered
  __shared__ float outt[3][3][16];               // [j][n][s] final Jacobian rows

  const int lane  = threadIdx.x & 63;
  const int w     = threadIdx.x >> 6;   // 0 = primal, 1..3 = tangent j=w-1
  const int s     = lane & 15;          // sample column
  const int g     = lane >> 4;
  const int sbase = blockIdx.x << 4;    // 16 samples per block

  const f16x8* __restrict__ whp = (const f16x8*)(ws + OFF_WHP);
  const f16x8* __restrict__ wlp = (const f16x8*)(ws + OFF_WLP);
  const f32x4* __restrict__ w0p = (const f32x4*)(ws + OFF_W0P);
  const float* __restrict__ b0p = (const float*)(ws + OFF_B0P);
  const float* __restrict__ gp  = (const float*)(ws + OFF_GP);
  const f32x4* __restrict__ bhp = (const f32x4*)(ws + OFF_BHP);

  f16x8 st[8];    // primal: current h frags (B-slot order)
  f16x8 nst[8];   // next-state (primal h / unmasked tangent preact)

  // ---- phase 0: primal layer0 + Wh0, masks0 -> mbuf[0] ----
  if (w==0){
    const f32x4 xv = ((const f32x4*)x)[sbase + s];
    #pragma unroll
    for(int kk=0;kk<8;kk++){
      f16x8 v;
      #pragma unroll
      for(int e=0;e<8;e++){
        f32x4 wv = w0p[(kk*64+lane)*8+e];
        float b  = b0p[(kk*64+lane)*8+e];
        float h = fmaf(xv[3],wv[3], fmaf(xv[2],wv[2], fmaf(xv[1],wv[1], fmaf(xv[0],wv[0], b))));
        v[e] = (f16)h;
      }
      st[kk] = v;
    }
    #pragma unroll
    for(int nt=0;nt<16;nt++){
      f32x4 acc = {0.f,0.f,0.f,0.f};
      #pragma unroll
      for(int kk=0;kk<8;kk++)
        acc = __builtin_amdgcn_mfma_f32_16x16x32_f16(whp[(nt*8+kk)*64+lane], st[kk], acc, 0,0,0);
      f32x4 bv = bhp[nt*64+lane];
      f16x4 mv;
      #pragma unroll
      for(int r=0;r<4;r++){
        float h = tanh_fast(acc[r]+bv[r]);
        nst[nt>>1][(nt&1)*4+r] = (f16)h;
        mv[r] = (f16)(1.f - h*h);
      }
      *(f16x4*)(&mbuf[0][0] + moff(s, nt*16 + 4*g)) = mv;
    }
    #pragma unroll
    for(int kk=0;kk<8;kk++) st[kk]=nst[kk];
  }
  __syncthreads();

  // ---- phases 1..4: primal layer p || tangent layer p (uses masks p-1) ----
  #pragma unroll 1
  for(int p=1;p<5;p++){
    const f16x8* wl = whp + p*8192;
    if (w==0){
      const f32x4* bp = bhp + p*1024;
      char* mb = &mbuf[p&1][0];
      #pragma unroll
      for(int nt=0;nt<16;nt++){
        f32x4 acc = {0.f,0.f,0.f,0.f};
        #pragma unroll
        for(int kk=0;kk<8;kk++)
          acc = __builtin_amdgcn_mfma_f32_16x16x32_f16(wl[(nt*8+kk)*64+lane], st[kk], acc, 0,0,0);
        f32x4 bv = bp[nt*64+lane];
        f16x4 mv;
        #pragma unroll
        for(int r=0;r<4;r++){
          float h = tanh_fast(acc[r]+bv[r]);
          nst[nt>>1][(nt&1)*4+r] = (f16)h;
          mv[r] = (f16)(1.f - h*h);
        }
        *(f16x4*)(mb + moff(s, nt*16 + 4*g)) = mv;
      }
      #pragma unroll
      for(int kk=0;kk<8;kk++) st[kk]=nst[kk];
    } else {
      const char* mb = &mbuf[(p-1)&1][0];
      f16x8 bf[8];
      if (p==1){
        const int j = w-1;
        #pragma unroll
        for(int kk=0;kk<8;kk++){
          f16x4 mlo = *(const f16x4*)(mb + moff(s,(2*kk+0)*16+4*g));
          f16x4 mhi = *(const f16x4*)(mb + moff(s,(2*kk+1)*16+4*g));
          f16x4 lo, hi;
          #pragma unroll
          for(int r=0;r<4;r++){
            lo[r] = (f16)((float)mlo[r] * gp[((j*8+kk)*64+lane)*8 + r]);
            hi[r] = (f16)((float)mhi[r] * gp[((j*8+kk)*64+lane)*8 + 4 + r]);
          }
          bf[kk] = __builtin_shufflevector(lo, hi, 0,1,2,3,4,5,6,7);
        }
      } else {
        #pragma unroll
        for(int kk=0;kk<8;kk++){
          f16x4 mlo = *(const f16x4*)(mb + moff(s,(2*kk+0)*16+4*g));
          f16x4 mhi = *(const f16x4*)(mb + moff(s,(2*kk+1)*16+4*g));
          f16x8 m8 = __builtin_shufflevector(mlo, mhi, 0,1,2,3,4,5,6,7);
          bf[kk] = m8 * nst[kk];
        }
      }
      #pragma unroll
      for(int nt=0;nt<16;nt++){
        f32x4 acc = {0.f,0.f,0.f,0.f};
        #pragma unroll
        for(int kk=0;kk<8;kk++)
          acc = __builtin_amdgcn_mfma_f32_16x16x32_f16(wl[(nt*8+kk)*64+lane], bf[kk], acc, 0,0,0);
        #pragma unroll
        for(int r=0;r<4;r++) nst[nt>>1][(nt&1)*4+r] = (f16)acc[r];
      }
    }
    __syncthreads();
  }

  // ---- phase 5: tangent final (mask4 in mbuf[0]) -> Wl, rows to LDS ----
  if (w>0){
    const char* mb = &mbuf[0][0];
    f16x8 bf[8];
    #pragma unroll
    for(int kk=0;kk<8;kk++){
      f16x4 mlo = *(const f16x4*)(mb + moff(s,(2*kk+0)*16+4*g));
      f16x4 mhi = *(const f16x4*)(mb + moff(s,(2*kk+1)*16+4*g));
      f16x8 m8 = __builtin_shufflevector(mlo, mhi, 0,1,2,3,4,5,6,7);
      bf[kk] = m8 * nst[kk];
    }
    f32x4 acc = {0.f,0.f,0.f,0.f};
    #pragma unroll
    for(int kk=0;kk<8;kk++)
      acc = __builtin_amdgcn_mfma_f32_16x16x32_f16(wlp[kk*64+lane], bf[kk], acc, 0,0,0);
    // D: col=lane&15=s, row=(lane>>4)*4+reg -> lanes 0..15 hold rows 0..3
    if (lane<16){
      outt[w-1][0][lane] = acc[0];
      outt[w-1][1][lane] = acc[1];
      outt[w-1][2][lane] = acc[2];
    }
  }
  __syncthreads();

  if (w==0 && lane<16){
    const int so = (sbase + lane)*3;
    out[so+0] = outt[1][2][lane] - outt[2][1][lane];  // da2/dx1 - da1/dx2
    out[so+1] = outt[2][0][lane] - outt[0][2][lane];  // da0/dx2 - da2/dx0
    out[so+2] = outt[0][1][lane] - outt[1][0][lane];  // da1/dx0 - da0/dx1
  }
}

extern "C" void kernel_launch(void* const* d_in, const int* in_sizes, int n_in,
                              void* d_out, int out_size, void* d_ws, size_t ws_size,
                              hipStream_t stream){
  const float* x  = (const float*)d_in[0];
  const float* W0 = (const float*)d_in[1];
  const float* b0 = (const float*)d_in[2];
  const float* Wh = (const float*)d_in[3];
  const float* bh = (const float*)d_in[4];
  const float* Wl = (const float*)d_in[5];
  // d_in[6] = bl: constant offset of a, curl kills it.
  prepack<<<1440, 256, 0, stream>>>(W0, b0, Wh, bh, Wl, (unsigned char*)d_ws);
  velcurl<<<4096, 256, 0, stream>>>(x, (const unsigned char*)d_ws, (float*)d_out);
}